// Round 1
// baseline (327.803 us; speedup 1.0000x reference)
//
#include <hip/hip_runtime.h>

#define S_LEN 2048
#define D_DIM 128

typedef float f4 __attribute__((ext_vector_type(4)));
typedef __bf16 y8 __attribute__((ext_vector_type(8)));
typedef short s4v __attribute__((ext_vector_type(4)));

union Frag {
  unsigned u[4];
  unsigned short h[8];
  y8 v;
};

// round-to-nearest-even f32 -> bf16 (inputs are normal floats; no NaN handling needed)
__device__ __forceinline__ unsigned short f2bf(float f) {
  unsigned u = __float_as_uint(f);
  return (unsigned short)((u + 0x7fffu + ((u >> 16) & 1u)) >> 16);
}

// Flash-attention fwd, causal. 4 waves/block, wave owns 16 q-rows, KV tile = 32.
// Swapped QK^T: S^T = K·Q^T so each lane's softmax row is q = lane&15.
__global__ __launch_bounds__(256, 4) void fattn_kernel(
    const float* __restrict__ Qg0, const float* __restrict__ Kg0,
    const float* __restrict__ Vg0, float* __restrict__ Og0) {
  // K tile: [32][128] bf16, XOR-swizzled within row (8-elem chunks)
  __shared__ __align__(16) unsigned short kbuf[32 * 128];
  // V tile transposed: [d=128][k=40(pad)] bf16
  __shared__ __align__(16) unsigned short vtbuf[128 * 40];

  const int qb  = blockIdx.x;   // q-tile of 64 rows
  const int bh  = blockIdx.y;   // b*H + h
  const int tid = threadIdx.x;
  const int w   = tid >> 6;
  const int l   = tid & 63;
  const int g   = l >> 4;       // 16-lane group 0..3
  const int qi  = l & 15;

  const int wq    = qb * 64 + w * 16;  // wave's first q row
  const int q_abs = wq + qi;           // this lane's softmax row

  const size_t base = (size_t)bh * S_LEN * D_DIM;
  const float* Qg = Qg0 + base;
  const float* Kg = Kg0 + base;
  const float* Vg = Vg0 + base;
  float*       Og = Og0 + base;

  // ---- Q fragments in registers (scaled by 1/sqrt(D)) ----
  // B-frag for mfma(K, Q^T): lane holds Q[q=lane&15][d = c*32 + g*8 + j]
  Frag qf[4];
  {
    const float sc = 0.08838834764831845f;  // 1/sqrt(128)
    const float* qrow = Qg + (size_t)q_abs * D_DIM + g * 8;
#pragma unroll
    for (int c = 0; c < 4; ++c) {
      float4 f0 = *(const float4*)(qrow + c * 32);
      float4 f1 = *(const float4*)(qrow + c * 32 + 4);
      qf[c].h[0] = f2bf(f0.x * sc); qf[c].h[1] = f2bf(f0.y * sc);
      qf[c].h[2] = f2bf(f0.z * sc); qf[c].h[3] = f2bf(f0.w * sc);
      qf[c].h[4] = f2bf(f1.x * sc); qf[c].h[5] = f2bf(f1.y * sc);
      qf[c].h[6] = f2bf(f1.z * sc); qf[c].h[7] = f2bf(f1.w * sc);
    }
  }

  f4 acc[8];
#pragma unroll
  for (int i = 0; i < 8; ++i) acc[i] = (f4){0.f, 0.f, 0.f, 0.f};
  float m_run = -3.0e38f;
  float l_run = 0.f;

  const int nkt = 2 * qb + 2;  // tiles cover k <= qb*64+63

  const int sk  = tid >> 3;   // K-stage row 0..31
  const int sc8 = tid & 7;    // K-stage col-group
  const int sd4 = tid & 31;   // V-stage d-chunk
  const int skp = tid >> 5;   // V-stage k-group 0..7

  for (int kt = 0; kt < nkt; ++kt) {
    const int kb = kt * 32;
    __syncthreads();  // protect LDS from previous iteration's readers

    // ---- stage K tile (f32 -> bf16, swizzled) ----
#pragma unroll
    for (int p = 0; p < 2; ++p) {
      const int col8 = p * 8 + sc8;  // 8-float group 0..15
      const float* src = Kg + (size_t)(kb + sk) * D_DIM + col8 * 8;
      float4 f0 = *(const float4*)src;
      float4 f1 = *(const float4*)(src + 4);
      Frag t;
      t.h[0] = f2bf(f0.x); t.h[1] = f2bf(f0.y); t.h[2] = f2bf(f0.z); t.h[3] = f2bf(f0.w);
      t.h[4] = f2bf(f1.x); t.h[5] = f2bf(f1.y); t.h[6] = f2bf(f1.z); t.h[7] = f2bf(f1.w);
      const int so = (col8 * 8) ^ ((sk & 7) << 3);
      *(y8*)&kbuf[sk * 128 + so] = t.v;
    }

    // ---- stage V tile transposed: vtbuf[d][k] ----
    {
      const int k0 = skp * 4, d0 = sd4 * 4;
      const float* vsrc = Vg + (size_t)(kb + k0) * D_DIM + d0;
      float4 r0 = *(const float4*)(vsrc);
      float4 r1 = *(const float4*)(vsrc + D_DIM);
      float4 r2 = *(const float4*)(vsrc + 2 * D_DIM);
      float4 r3 = *(const float4*)(vsrc + 3 * D_DIM);
      *(s4v*)&vtbuf[(d0 + 0) * 40 + k0] =
          (s4v){(short)f2bf(r0.x), (short)f2bf(r1.x), (short)f2bf(r2.x), (short)f2bf(r3.x)};
      *(s4v*)&vtbuf[(d0 + 1) * 40 + k0] =
          (s4v){(short)f2bf(r0.y), (short)f2bf(r1.y), (short)f2bf(r2.y), (short)f2bf(r3.y)};
      *(s4v*)&vtbuf[(d0 + 2) * 40 + k0] =
          (s4v){(short)f2bf(r0.z), (short)f2bf(r1.z), (short)f2bf(r2.z), (short)f2bf(r3.z)};
      *(s4v*)&vtbuf[(d0 + 3) * 40 + k0] =
          (s4v){(short)f2bf(r0.w), (short)f2bf(r1.w), (short)f2bf(r2.w), (short)f2bf(r3.w)};
    }
    __syncthreads();

    if (kb > wq) continue;  // entire tile is future for this wave

    // ---- QK^T: S^T[k][q] accumulated over 4 d-chunks ----
    f4 s0 = (f4){0.f, 0.f, 0.f, 0.f};  // k rows 0..15 of tile
    f4 s1 = (f4){0.f, 0.f, 0.f, 0.f};  // k rows 16..31
#pragma unroll
    for (int c = 0; c < 4; ++c) {
      const int so = (c * 32 + g * 8) ^ ((qi & 7) << 3);
      y8 a0 = *(const y8*)&kbuf[qi * 128 + so];
      y8 a1 = *(const y8*)&kbuf[(qi + 16) * 128 + so];  // same swizzle ((qi+16)&7 == qi&7)
      s0 = __builtin_amdgcn_mfma_f32_16x16x32_bf16(a0, qf[c].v, s0, 0, 0, 0);
      s1 = __builtin_amdgcn_mfma_f32_16x16x32_bf16(a1, qf[c].v, s1, 0, 0, 0);
    }

    // ---- causal mask (diagonal tiles only) ----
    if (kb + 31 > wq) {
      const int kl = kb + g * 4;
#pragma unroll
      for (int r = 0; r < 4; ++r) {
        if (kl + r > q_abs)      s0[r] = -3.0e38f;
        if (kl + 16 + r > q_abs) s1[r] = -3.0e38f;
      }
    }

    // ---- online softmax; state (m,l) per q = lane&15, replicated over groups ----
    float tmax = fmaxf(fmaxf(fmaxf(s0[0], s0[1]), fmaxf(s0[2], s0[3])),
                       fmaxf(fmaxf(s1[0], s1[1]), fmaxf(s1[2], s1[3])));
    tmax = fmaxf(tmax, __shfl_xor(tmax, 16));
    tmax = fmaxf(tmax, __shfl_xor(tmax, 32));
    const float mnew = fmaxf(m_run, tmax);
    const float scl  = __expf(m_run - mnew);  // first tile: exp(-3e38) = 0
    float p0 = __expf(s0[0] - mnew), p1 = __expf(s0[1] - mnew);
    float p2 = __expf(s0[2] - mnew), p3 = __expf(s0[3] - mnew);
    float p4 = __expf(s1[0] - mnew), p5 = __expf(s1[1] - mnew);
    float p6 = __expf(s1[2] - mnew), p7 = __expf(s1[3] - mnew);
    float rs = ((p0 + p1) + (p2 + p3)) + ((p4 + p5) + (p6 + p7));
    rs += __shfl_xor(rs, 16);
    rs += __shfl_xor(rs, 32);
    l_run = l_run * scl + rs;
    m_run = mnew;

    // rescale O accumulator: acc rows are q' = g*4+r; scale lives at lane q'
    f4 srv;
    srv[0] = __shfl(scl, g * 4 + 0);
    srv[1] = __shfl(scl, g * 4 + 1);
    srv[2] = __shfl(scl, g * 4 + 2);
    srv[3] = __shfl(scl, g * 4 + 3);
#pragma unroll
    for (int ch = 0; ch < 8; ++ch) acc[ch] *= srv;

    // ---- redistribute P (S^T layout) into PV A-fragment (P layout) ----
    // lane holds p for (q=lane&15, k = {4g..4g+3, 16+4g..16+4g+3});
    // A-frag needs (q=lane&15, k = 8g..8g+7) -> gather from lanes bs, bs+16.
    const unsigned w0 = (unsigned)f2bf(p0) | ((unsigned)f2bf(p1) << 16);
    const unsigned w1 = (unsigned)f2bf(p2) | ((unsigned)f2bf(p3) << 16);
    const unsigned w2 = (unsigned)f2bf(p4) | ((unsigned)f2bf(p5) << 16);
    const unsigned w3 = (unsigned)f2bf(p6) | ((unsigned)f2bf(p7) << 16);
    const int  bs = ((l >> 4) & 1) * 32 + qi;
    const bool hi = (l >= 32);
    unsigned t0  = __shfl(w0, bs),      t2  = __shfl(w2, bs);
    unsigned t1  = __shfl(w1, bs),      t3  = __shfl(w3, bs);
    unsigned t0b = __shfl(w0, bs + 16), t2b = __shfl(w2, bs + 16);
    unsigned t1b = __shfl(w1, bs + 16), t3b = __shfl(w3, bs + 16);
    Frag pa;
    pa.u[0] = hi ? t2  : t0;
    pa.u[1] = hi ? t3  : t1;
    pa.u[2] = hi ? t2b : t0b;
    pa.u[3] = hi ? t3b : t1b;

    // ---- PV: O[q][d] += P·V, B-frag = Vt[d0+qi][8g..8g+7] ----
#pragma unroll
    for (int ch = 0; ch < 8; ++ch) {
      y8 bv = *(const y8*)&vtbuf[(ch * 16 + qi) * 40 + g * 8];
      acc[ch] = __builtin_amdgcn_mfma_f32_16x16x32_bf16(pa.v, bv, acc[ch], 0, 0, 0);
    }
  }

  // ---- epilogue: divide by l and store (acc row q' = g*4+r, col d = ch*16+qi) ----
  f4 li;
  li[0] = 1.0f / __shfl(l_run, g * 4 + 0);
  li[1] = 1.0f / __shfl(l_run, g * 4 + 1);
  li[2] = 1.0f / __shfl(l_run, g * 4 + 2);
  li[3] = 1.0f / __shfl(l_run, g * 4 + 3);
#pragma unroll
  for (int ch = 0; ch < 8; ++ch) {
#pragma unroll
    for (int r = 0; r < 4; ++r) {
      Og[(size_t)(wq + g * 4 + r) * D_DIM + ch * 16 + qi] = acc[ch][r] * li[r];
    }
  }
}

extern "C" void kernel_launch(void* const* d_in, const int* in_sizes, int n_in,
                              void* d_out, int out_size, void* d_ws, size_t ws_size,
                              hipStream_t stream) {
  const float* Q = (const float*)d_in[0];
  const float* K = (const float*)d_in[1];
  const float* V = (const float*)d_in[2];
  // d_in[3] is the causal triu mask — semantics hardcoded in-kernel.
  float* O = (float*)d_out;
  dim3 grid(S_LEN / 64, 32);  // (q-tile, B*H)
  fattn_kernel<<<grid, 256, 0, stream>>>(Q, K, V, O);
}